// Round 1
// baseline (366.089 us; speedup 1.0000x reference)
//
#include <hip/hip_runtime.h>
#include <hip/hip_bf16.h>

#define VOCAB 50000
#define EMB   300
#define FILT  400
#define ATT   200
#define BB    4096
#define NN    30

#define ATTP  208        // att padded to 13 n-tiles
#define CLS   424        // fused-epilogue C-tile row stride in ushorts (848 B: 16B-aligned, 2-way-free b128 reads)

typedef short bf16x8 __attribute__((ext_vector_type(8)));
typedef float f32x4  __attribute__((ext_vector_type(4)));
typedef unsigned short u16x4 __attribute__((ext_vector_type(4)));

static __device__ __forceinline__ unsigned short f2bf(float f) {
    __hip_bfloat16 h = __float2bfloat16(f);
    union { __hip_bfloat16 h; unsigned short u; } c; c.h = h; return c.u;
}
static __device__ __forceinline__ float bf2f(unsigned short u) {
    union { unsigned int u; float f; } c; c.u = ((unsigned int)u) << 16; return c.f;
}
// numerics validated (R3 first-pass absmax 3.8e-6)
static __device__ __forceinline__ float fast_tanh(float x) {
    float e = __expf(2.f * x);
    return 1.f - 2.f * __builtin_amdgcn_rcpf(e + 1.f);
}

// async global->LDS DMA, 16 B per lane; lds dest = wave-uniform base + lane*16
static __device__ __forceinline__ void dma16(const unsigned short* g, unsigned short* l) {
    __builtin_amdgcn_global_load_lds(
        (const __attribute__((address_space(1))) unsigned int*)(const void*)g,
        (__attribute__((address_space(3))) unsigned int*)(void*)l,
        16, 0, 0);
}

// ---------------- prep: lane-major fragment tiles ----------------
// Bc2 tile tau=(k*10+es)*25+ft, 512 ushorts; pos = lane*8+j holds
//   B[f=ft*16+(lane&15)][e=es*32+(lane>>4)*8+j]  (zero for e>=300)
// Bv2 tile tau=ks*13+at; pos = lane*8+j holds
//   v[fcol=ks*32+(lane>>4)*8+j][att=at*16+(lane&15)]  (zero-padded)
__global__ __launch_bounds__(256) void kP(const float* __restrict__ conv_w,
                                          const float* __restrict__ v,
                                          const float* __restrict__ vb,
                                          const float* __restrict__ q,
                                          unsigned short* __restrict__ Bc2,
                                          unsigned short* __restrict__ Bv2,
                                          float* __restrict__ vbp,
                                          float* __restrict__ qp) {
    int t = blockIdx.x * 256 + threadIdx.x;
    const int NBC = 750 * 512;               // 384,000
    if (t < NBC) {
        int tau = t >> 9, off = t & 511;
        int l = off >> 3, j = off & 7;
        int lm = l & 15, qq = l >> 4;
        int ft = tau % 25, es = (tau / 25) % 10, k = tau / 250;
        int f = ft * 16 + lm;
        int e = es * 32 + qq * 8 + j;
        float val = (e < EMB) ? conv_w[((size_t)f * EMB + e) * 3 + k] : 0.f;
        Bc2[t] = f2bf(val);
    } else {
        int t2 = t - NBC;
        if (t2 < 169 * 512) {                // 86,528
            int tau = t2 >> 9, off = t2 & 511;
            int l = off >> 3, j = off & 7;
            int lm = l & 15, qq = l >> 4;
            int ks = tau / 13, at = tau % 13;
            int att = at * 16 + lm;
            int fcol = ks * 32 + qq * 8 + j;
            float val = (att < ATT && fcol < FILT) ? v[(size_t)fcol * ATT + att] : 0.f;
            Bv2[t2] = f2bf(val);
        }
    }
    if (t < ATTP) {
        vbp[t] = (t < ATT) ? vb[t] : 0.f;
        qp[t]  = (t < ATT) ? q[t] : 0.f;
    }
}

// gather 8 consecutive emb cols (fp32) for one token into aR; zeros when invalid
static __device__ __forceinline__ void gatherA(const float* __restrict__ emb,
                                               int tok, int e, float* aR) {
#pragma unroll
    for (int jj = 0; jj < 8; jj++) aR[jj] = 0.f;
    if (tok >= 0 && e < EMB) {
        if (e <= 292) {
            float4 x = *(const float4*)(emb + (size_t)tok * EMB + e);
            float4 y = *(const float4*)(emb + (size_t)tok * EMB + e + 4);
            aR[0] = x.x; aR[1] = x.y; aR[2] = x.z; aR[3] = x.w;
            aR[4] = y.x; aR[5] = y.y; aR[6] = y.z; aR[7] = y.w;
        } else {
#pragma unroll
            for (int jj = 0; jj < 8; jj++) {
                int ee = e + jj;
                if (ee < EMB) aR[jj] = emb[(size_t)tok * EMB + ee];
            }
        }
    }
}

// ---------------- k1: pipelined conv GEMM + fused attention-logit epilogue ----------------
// Main loop identical to the verified m97-style schedule (30 K-steps of 32, DMA dbuf).
// Epilogue: per 64-row half, stage relu(C) (bf16) into LDS (union over As/Bs),
// run the 64x208x416 attention GEMM with B straight from L2-resident Bv2 tiles,
// tanh*q, lane-group + cross-wave reduce, write logits a[n][b] to aG (d_out scratch).
__global__ __launch_bounds__(640, 2) void k1_conv(
    const int* __restrict__ idx,
    const float* __restrict__ emb,
    const unsigned short* __restrict__ Bc2,
    const float* __restrict__ conv_b,
    const unsigned short* __restrict__ Bv2,
    const float* __restrict__ vbp,
    const float* __restrict__ qp,
    unsigned short* __restrict__ Cws,
    float* __restrict__ aG)
{
    __shared__ union {
        struct { unsigned short As[131 * 40]; unsigned short Bs[2 * 25 * 512]; } mm;  // 61,680 B
        struct { unsigned short Cl[64 * CLS]; float wp[160]; } at;                    // 54,912 B
    } sh;
    unsigned short* const As = sh.mm.As;
    unsigned short* const Bs = sh.mm.Bs;

    const int bid = blockIdx.x;
    const int t = threadIdx.x;
    const int lane = t & 63, wave = t >> 6;
    const int lm = lane & 15, qq = lane >> 4;
    const int wg = wave / 5, fw = wave % 5;
    const int rbase = wg * 64;

    // A-gather unit: thread t -> row uj, 8-col segment useg
    const int uj = t >> 2, useg = t & 3;
    const bool uact = (t < 524);                  // 131 rows x 4 segs
    int utok = -1;
    if (uact && uj < 128) {
        int ub = uj >> 5, uj2 = uj & 31;
        if (uj2 >= 1 && uj2 <= 30) utok = idx[(bid * 4 + ub) * NN + (uj2 - 1)];
    }

    // prologue: DMA K-steps 0,1 (wg0 waves stage their own 5 f-tiles)
    if (wg == 0) {
#pragma unroll
        for (int s = 0; s < 2; s++) {
#pragma unroll
            for (int nt = 0; nt < 5; nt++) {
                int gt = (s % 3) * 250 + (s / 3) * 25 + fw * 5 + nt;   // (k*10+es)*25+ft
                dma16(Bc2 + (size_t)gt * 512 + lane * 8,
                      Bs + s * 12800 + (fw * 5 + nt) * 512);
            }
        }
    }
    float aR[8];
    gatherA(emb, utok, useg * 8, aR);             // chunk 0

    f32x4 acc[4][5];
#pragma unroll
    for (int mt = 0; mt < 4; mt++)
#pragma unroll
        for (int nt = 0; nt < 5; nt++)
            acc[mt][nt] = (f32x4){0.f, 0.f, 0.f, 0.f};

    for (int es = 0; es < 10; ++es) {
        // publish A chunk es (aR loaded >= 1 full chunk ago)
        if (uact) {
            union { bf16x8 v; unsigned short u[8]; } cv;
#pragma unroll
            for (int jj = 0; jj < 8; jj++) cv.u[jj] = f2bf(aR[jj]);
            *(bf16x8*)(As + uj * 40 + useg * 8) = cv.v;
        }
        __syncthreads();                           // As visible; also drains pending DMA
        if (es < 9) gatherA(emb, utok, (es + 1) * 32 + useg * 8, aR);

#pragma unroll
        for (int k = 0; k < 3; ++k) {
            const int s = es * 3 + k;
            const unsigned short* bb = Bs + (s & 1) * 12800;
            bf16x8 aF[4];
#pragma unroll
            for (int mt = 0; mt < 4; mt++)
                aF[mt] = *(const bf16x8*)(As + (rbase + mt * 16 + lm + k) * 40 + qq * 8);
#pragma unroll
            for (int nt = 0; nt < 5; nt++) {
                bf16x8 bF = *(const bf16x8*)(bb + (fw * 5 + nt) * 512 + lane * 8);
#pragma unroll
                for (int mt = 0; mt < 4; mt++)
                    acc[mt][nt] = __builtin_amdgcn_mfma_f32_16x16x32_bf16(aF[mt], bF, acc[mt][nt], 0, 0, 0);
            }
            __syncthreads();                       // buf[s&1] free; DMA(s+1) already drained
            if (s + 2 < 30 && wg == 0) {
                const int s2 = s + 2, es2 = s2 / 3, k2 = s2 - es2 * 3;
#pragma unroll
                for (int nt = 0; nt < 5; nt++) {
                    int gt = (k2 * 10 + es2) * 25 + fw * 5 + nt;
                    dma16(Bc2 + (size_t)gt * 512 + lane * 8,
                          Bs + (s & 1) * 12800 + (fw * 5 + nt) * 512);
                }
            }
        }
    }

    // ---- fused epilogue ----
    const int f0 = fw * 80;
    float cb[5];
#pragma unroll
    for (int nt = 0; nt < 5; nt++) cb[nt] = conv_b[f0 + nt * 16 + lm];

    const int rt = wave & 3;             // attention row-tile (fixed per wave -> static rsum)
    const int widx = wave >> 2;
    const int nW = (rt < 2) ? 3 : 2;     // waves sharing this rt: rt0/rt1 x3, rt2/rt3 x2

#pragma unroll
    for (int h = 0; h < 2; ++h) {
        // stage this half's relu(C) into LDS + global Cws write (h1 staging is safe:
        // h0's Cl reads finished before the barrier that released h0's wp values)
        if (wg == h) {
#pragma unroll
            for (int mt = 0; mt < 4; mt++) {
#pragma unroll
                for (int r = 0; r < 4; r++) {
                    int lr = mt * 16 + qq * 4 + r;            // local row 0..63
                    int lrow = h * 64 + lr;
                    int pos = lrow & 31, grp = lrow >> 5;
#pragma unroll
                    for (int nt = 0; nt < 5; nt++) {
                        float vv = fmaxf(acc[mt][nt][r] + cb[nt], 0.f);
                        unsigned short bv = f2bf(vv);
                        sh.at.Cl[lr * CLS + f0 + nt * 16 + lm] = bv;
                        if (pos < NN)
                            Cws[((size_t)(bid * 4 + grp) * NN + pos) * FILT + f0 + nt * 16 + lm] = bv;
                    }
                }
            }
        }
        if (h == 0) {
            // zero att-K pad cols 400..415 once (NaN-safe: MFMA 0*NaN=NaN); persists into h1
            for (int i = t; i < 64 * 16; i += 640)
                sh.at.Cl[(i >> 4) * CLS + 400 + (i & 15)] = 0;
        }
        __syncthreads();                           // Cl (and pad zeros) visible

        float rs0 = 0.f, rs1 = 0.f, rs2 = 0.f, rs3 = 0.f;
        for (int ct = widx; ct < 13; ct += nW) {
            f32x4 sA = (f32x4){0.f, 0.f, 0.f, 0.f};
            f32x4 sB = (f32x4){0.f, 0.f, 0.f, 0.f};
#pragma unroll
            for (int ks = 0; ks < 13; ks++) {
                bf16x8 aF = *(const bf16x8*)(sh.at.Cl + (rt * 16 + lm) * CLS + ks * 32 + qq * 8);
                bf16x8 bF = *(const bf16x8*)(Bv2 + (size_t)(ks * 13 + ct) * 512 + lane * 8);
                if (ks & 1) sB = __builtin_amdgcn_mfma_f32_16x16x32_bf16(aF, bF, sB, 0, 0, 0);
                else        sA = __builtin_amdgcn_mfma_f32_16x16x32_bf16(aF, bF, sA, 0, 0, 0);
            }
            int att = ct * 16 + lm;
            float vbv = vbp[att], qv = qp[att];     // padded att: acc=0, q=0 -> 0
            float p0 = fast_tanh(sA[0] + sB[0] + vbv) * qv;
            float p1 = fast_tanh(sA[1] + sB[1] + vbv) * qv;
            float p2 = fast_tanh(sA[2] + sB[2] + vbv) * qv;
            float p3 = fast_tanh(sA[3] + sB[3] + vbv) * qv;
#pragma unroll
            for (int off = 1; off < 16; off <<= 1) {
                p0 += __shfl_xor(p0, off, 64);
                p1 += __shfl_xor(p1, off, 64);
                p2 += __shfl_xor(p2, off, 64);
                p3 += __shfl_xor(p3, off, 64);
            }
            if (lm == 0) { rs0 += p0; rs1 += p1; rs2 += p2; rs3 += p3; }
        }
        if (lm == 0) {
            sh.at.wp[wave * 16 + qq * 4 + 0] = rs0;
            sh.at.wp[wave * 16 + qq * 4 + 1] = rs1;
            sh.at.wp[wave * 16 + qq * 4 + 2] = rs2;
            sh.at.wp[wave * 16 + qq * 4 + 3] = rs3;
        }
        __syncthreads();                           // wp visible
        if (t < 64) {
            int rr = t >> 4, ii = t & 15;
            float sum = 0.f;
            for (int w = rr; w < 10; w += 4) sum += sh.at.wp[w * 16 + ii];  // waves with rt==rr
            int lrow = h * 64 + t;
            int pos = lrow & 31, grp = lrow >> 5;
            if (pos < NN) aG[(size_t)pos * BB + bid * 4 + grp] = sum;       // a[n][b] layout
        }
    }
}

// ---------------- k3: softmax over batch dim, coalesced [n][b] layout ----------------
// reads a (d_out scratch), writes masked alpha into the now-dead Bc2 region
__global__ __launch_bounds__(1024) void k3_softmax(const float* __restrict__ a,
                                                   float* __restrict__ alpha,
                                                   const int* __restrict__ idx) {
    int n = blockIdx.x, tid = threadIdx.x;
    float4 v4 = *(const float4*)(a + (size_t)n * BB + tid * 4);
    float m = fmaxf(fmaxf(v4.x, v4.y), fmaxf(v4.z, v4.w));
    __shared__ float red[32];
#pragma unroll
    for (int off = 32; off >= 1; off >>= 1) m = fmaxf(m, __shfl_xor(m, off, 64));
    int wv = tid >> 6;
    if ((tid & 63) == 0) red[wv] = m;
    __syncthreads();
#pragma unroll
    for (int w = 0; w < 16; w++) m = fmaxf(m, red[w]);
    float e0 = expf(v4.x - m), e1 = expf(v4.y - m);
    float e2 = expf(v4.z - m), e3 = expf(v4.w - m);
    float s = e0 + e1 + e2 + e3;
#pragma unroll
    for (int off = 32; off >= 1; off >>= 1) s += __shfl_xor(s, off, 64);
    if ((tid & 63) == 0) red[16 + wv] = s;
    __syncthreads();
    s = 0.f;
#pragma unroll
    for (int w = 0; w < 16; w++) s += red[16 + w];
    float inv = 1.f / s;
    int b0 = tid * 4;
    float4 o;
    o.x = e0 * inv * ((idx[(size_t)(b0 + 0) * NN + n] != 0) ? 1.f : 0.f);
    o.y = e1 * inv * ((idx[(size_t)(b0 + 1) * NN + n] != 0) ? 1.f : 0.f);
    o.z = e2 * inv * ((idx[(size_t)(b0 + 2) * NN + n] != 0) ? 1.f : 0.f);
    o.w = e3 * inv * ((idx[(size_t)(b0 + 3) * NN + n] != 0) ? 1.f : 0.f);
    *(float4*)(alpha + (size_t)n * BB + b0) = o;
}

// ---------------- k4: weighted pooling, vectorized ----------------
__global__ __launch_bounds__(128) void k4_pool(
    const float* __restrict__ alpha, const unsigned short* __restrict__ C,
    float* __restrict__ out)
{
    int b = blockIdx.x;
    int tid = threadIdx.x;
    __shared__ float al[NN];
    if (tid < NN) al[tid] = alpha[(size_t)tid * BB + b];   // [n][b] layout
    __syncthreads();
    if (tid < 100) {
        int f = tid * 4;
        float s0 = 0.f, s1 = 0.f, s2 = 0.f, s3 = 0.f;
        const unsigned short* Cb = C + (size_t)b * (NN * FILT) + f;
#pragma unroll
        for (int n = 0; n < NN; n++) {
            u16x4 c = *(const u16x4*)(Cb + (size_t)n * FILT);
            float a = al[n];
            s0 = fmaf(a, bf2f(c[0]), s0);
            s1 = fmaf(a, bf2f(c[1]), s1);
            s2 = fmaf(a, bf2f(c[2]), s2);
            s3 = fmaf(a, bf2f(c[3]), s3);
        }
        float4 o; o.x = s0; o.y = s1; o.z = s2; o.w = s3;
        *(float4*)(out + (size_t)b * FILT + f) = o;
    }
}

extern "C" void kernel_launch(void* const* d_in, const int* in_sizes, int n_in,
                              void* d_out, int out_size, void* d_ws, size_t ws_size,
                              hipStream_t stream) {
    const int*   idx    = (const int*)d_in[0];
    const float* emb    = (const float*)d_in[1];
    const float* conv_w = (const float*)d_in[2];
    const float* conv_b = (const float*)d_in[3];
    const float* v      = (const float*)d_in[4];
    const float* vb     = (const float*)d_in[5];
    const float* q      = (const float*)d_in[6];
    float* out = (float*)d_out;

    // workspace (total 99,247,104 B <= 99,287,040 proven floor):
    //   Bv2 | vbp | qp | Bc2 (aliased by alpha after k1) | Cws
    // logits a[30][4096] live in d_out as scratch (k4 rewrites every element last)
    char* ws = (char*)d_ws;
    size_t o = 0;
    unsigned short* Bv2 = (unsigned short*)(ws + o); o += (size_t)169 * 512 * 2;      // 173,056
    float* vbp = (float*)(ws + o);                   o += 1024;
    float* qp  = (float*)(ws + o);                   o += 1024;                        // 175,104
    unsigned short* Bc2 = (unsigned short*)(ws + o);
    float* alpha = (float*)(ws + o);                 // alias of Bc2 (491,520 <= 768,000; Bc2 dead after k1)
    o += (size_t)750 * 512 * 2;                      // -> 943,104
    unsigned short* Cws = (unsigned short*)(ws + o);

    float* aG = out;                                 // d_out scratch for logits [n][b]

    const int NP = 750 * 512 + 169 * 512;            // 470,528
    kP<<<(NP + 255) / 256, 256, 0, stream>>>(conv_w, v, vb, q, Bc2, Bv2, vbp, qp);
    k1_conv<<<BB / 4, 640, 0, stream>>>(idx, emb, Bc2, conv_b, Bv2, vbp, qp, Cws, aG);
    k3_softmax<<<NN, 1024, 0, stream>>>(aG, alpha, idx);
    k4_pool<<<BB, 128, 0, stream>>>(alpha, Cws, out);
}

// Round 2
// 276.095 us; speedup vs baseline: 1.3260x; 1.3260x over previous
//
#include <hip/hip_runtime.h>
#include <hip/hip_bf16.h>

#define VOCAB 50000
#define EMB   300
#define FILT  400
#define ATT   200
#define BB    4096
#define NN    30

#define ATTP  208        // att padded to 13 n-tiles
#define KC    416        // padded K for attention GEMM (13 K-steps of 32)

typedef short bf16x8 __attribute__((ext_vector_type(8)));
typedef float f32x4  __attribute__((ext_vector_type(4)));
typedef unsigned short u16x4 __attribute__((ext_vector_type(4)));

static __device__ __forceinline__ unsigned short f2bf(float f) {
    __hip_bfloat16 h = __float2bfloat16(f);
    union { __hip_bfloat16 h; unsigned short u; } c; c.h = h; return c.u;
}
static __device__ __forceinline__ float bf2f(unsigned short u) {
    union { unsigned int u; float f; } c; c.u = ((unsigned int)u) << 16; return c.f;
}
// numerics validated (absmax 3.8e-6)
static __device__ __forceinline__ float fast_tanh(float x) {
    float e = __expf(2.f * x);
    return 1.f - 2.f * __builtin_amdgcn_rcpf(e + 1.f);
}

// async global->LDS DMA, 16 B per lane; lds dest = wave-uniform base + lane*16
static __device__ __forceinline__ void dma16(const unsigned short* g, unsigned short* l) {
    __builtin_amdgcn_global_load_lds(
        (const __attribute__((address_space(1))) unsigned int*)(const void*)g,
        (__attribute__((address_space(3))) unsigned int*)(void*)l,
        16, 0, 0);
}

// ---------------- prep: lane-major fragment tiles ----------------
// Bc2 tile tau=(k*10+es)*25+ft, 512 ushorts; pos = lane*8+j holds
//   B[f=ft*16+(lane&15)][e=es*32+(lane>>4)*8+j]  (zero for e>=300)
// Bv2 tile tau=ks*13+at; pos = lane*8+j holds
//   v[fcol=ks*32+(lane>>4)*8+j][att=at*16+(lane&15)]  (zero-padded)
// -> a wave DMA/ds_read of one tile is a verbatim contiguous 1 KB.
__global__ __launch_bounds__(256) void kP(const float* __restrict__ conv_w,
                                          const float* __restrict__ v,
                                          const float* __restrict__ vb,
                                          const float* __restrict__ q,
                                          unsigned short* __restrict__ Bc2,
                                          unsigned short* __restrict__ Bv2,
                                          float* __restrict__ vbp,
                                          float* __restrict__ qp) {
    int t = blockIdx.x * 256 + threadIdx.x;
    const int NBC = 750 * 512;               // 384,000
    if (t < NBC) {
        int tau = t >> 9, off = t & 511;
        int l = off >> 3, j = off & 7;
        int lm = l & 15, qq = l >> 4;
        int ft = tau % 25, es = (tau / 25) % 10, k = tau / 250;
        int f = ft * 16 + lm;
        int e = es * 32 + qq * 8 + j;
        float val = (e < EMB) ? conv_w[((size_t)f * EMB + e) * 3 + k] : 0.f;
        Bc2[t] = f2bf(val);
    } else {
        int t2 = t - NBC;
        if (t2 < 169 * 512) {                // 86,528
            int tau = t2 >> 9, off = t2 & 511;
            int l = off >> 3, j = off & 7;
            int lm = l & 15, qq = l >> 4;
            int ks = tau / 13, at = tau % 13;
            int att = at * 16 + lm;
            int fcol = ks * 32 + qq * 8 + j;
            float val = (att < ATT && fcol < FILT) ? v[(size_t)fcol * ATT + att] : 0.f;
            Bv2[t2] = f2bf(val);
        }
    }
    if (t < ATTP) {
        vbp[t] = (t < ATT) ? vb[t] : 0.f;
        qp[t]  = (t < ATT) ? q[t] : 0.f;
    }
}

// gather 8 consecutive emb cols (fp32) for one token into aR; zeros when invalid
static __device__ __forceinline__ void gatherA(const float* __restrict__ emb,
                                               int tok, int e, float* aR) {
#pragma unroll
    for (int jj = 0; jj < 8; jj++) aR[jj] = 0.f;
    if (tok >= 0 && e < EMB) {
        if (e <= 292) {
            float4 x = *(const float4*)(emb + (size_t)tok * EMB + e);
            float4 y = *(const float4*)(emb + (size_t)tok * EMB + e + 4);
            aR[0] = x.x; aR[1] = x.y; aR[2] = x.z; aR[3] = x.w;
            aR[4] = y.x; aR[5] = y.y; aR[6] = y.z; aR[7] = y.w;
        } else {
#pragma unroll
            for (int jj = 0; jj < 8; jj++) {
                int ee = e + jj;
                if (ee < EMB) aR[jj] = emb[(size_t)tok * EMB + ee];
            }
        }
    }
}

// ---------------- k1: m97-style pipelined conv GEMM ----------------
// 1024 blocks x 640 thr (10 waves = 2 row-groups x 5 f-waves), M=128 (4 batches).
// 30 K-steps of 32 (10 e-chunks x 3 taps). B: DMA double-buffer, one barrier/step,
// DMA for step s+2 issued after barrier s (drained one full step later).
// A: 32e chunk in LDS (rows 0..130; row j = batch j>>5, padded pos j&31),
// register-prefetched one chunk ahead.
__global__ __launch_bounds__(640, 2) void k1_conv(
    const int* __restrict__ idx,
    const float* __restrict__ emb,
    const unsigned short* __restrict__ Bc2,
    const float* __restrict__ conv_b,
    unsigned short* __restrict__ Cws)
{
    __shared__ unsigned short As[131 * 40];       // 10,480 B (stride 40 ush = 20 dw, 2-way-free)
    __shared__ unsigned short Bs[2 * 25 * 512];   // 51,200 B
    const int bid = blockIdx.x;
    const int t = threadIdx.x;
    const int lane = t & 63, wave = t >> 6;
    const int lm = lane & 15, qq = lane >> 4;
    const int wg = wave / 5, fw = wave % 5;
    const int rbase = wg * 64;

    // A-gather unit: thread t -> row uj, 8-col segment useg
    const int uj = t >> 2, useg = t & 3;
    const bool uact = (t < 524);                  // 131 rows x 4 segs
    int utok = -1;
    if (uact && uj < 128) {
        int ub = uj >> 5, uj2 = uj & 31;
        if (uj2 >= 1 && uj2 <= 30) utok = idx[(bid * 4 + ub) * NN + (uj2 - 1)];
    }

    // prologue: DMA K-steps 0,1 (wg0 waves stage their own 5 f-tiles)
    if (wg == 0) {
#pragma unroll
        for (int s = 0; s < 2; s++) {
#pragma unroll
            for (int nt = 0; nt < 5; nt++) {
                int gt = (s % 3) * 250 + (s / 3) * 25 + fw * 5 + nt;   // (k*10+es)*25+ft
                dma16(Bc2 + (size_t)gt * 512 + lane * 8,
                      Bs + s * 12800 + (fw * 5 + nt) * 512);
            }
        }
    }
    float aR[8];
    gatherA(emb, utok, useg * 8, aR);             // chunk 0

    f32x4 acc[4][5];
#pragma unroll
    for (int mt = 0; mt < 4; mt++)
#pragma unroll
        for (int nt = 0; nt < 5; nt++)
            acc[mt][nt] = (f32x4){0.f, 0.f, 0.f, 0.f};

    for (int es = 0; es < 10; ++es) {
        // publish A chunk es (aR loaded >= 1 full chunk ago)
        if (uact) {
            union { bf16x8 v; unsigned short u[8]; } cv;
#pragma unroll
            for (int jj = 0; jj < 8; jj++) cv.u[jj] = f2bf(aR[jj]);
            *(bf16x8*)(As + uj * 40 + useg * 8) = cv.v;
        }
        __syncthreads();                           // As visible; also drains pending DMA
        if (es < 9) gatherA(emb, utok, (es + 1) * 32 + useg * 8, aR);

#pragma unroll
        for (int k = 0; k < 3; ++k) {
            const int s = es * 3 + k;
            const unsigned short* bb = Bs + (s & 1) * 12800;
            bf16x8 aF[4];
#pragma unroll
            for (int mt = 0; mt < 4; mt++)
                aF[mt] = *(const bf16x8*)(As + (rbase + mt * 16 + lm + k) * 40 + qq * 8);
#pragma unroll
            for (int nt = 0; nt < 5; nt++) {
                bf16x8 bF = *(const bf16x8*)(bb + (fw * 5 + nt) * 512 + lane * 8);
#pragma unroll
                for (int mt = 0; mt < 4; mt++)
                    acc[mt][nt] = __builtin_amdgcn_mfma_f32_16x16x32_bf16(aF[mt], bF, acc[mt][nt], 0, 0, 0);
            }
            __syncthreads();                       // buf[s&1] free; DMA(s+1) already drained
            if (s + 2 < 30 && wg == 0) {
                const int s2 = s + 2, es2 = s2 / 3, k2 = s2 - es2 * 3;
#pragma unroll
                for (int nt = 0; nt < 5; nt++) {
                    int gt = (k2 * 10 + es2) * 25 + fw * 5 + nt;
                    dma16(Bc2 + (size_t)gt * 512 + lane * 8,
                          Bs + (s & 1) * 12800 + (fw * 5 + nt) * 512);
                }
            }
        }
    }

    // epilogue: bias + relu -> Cws (bf16)
    const int f0 = fw * 80;
    float cb[5];
#pragma unroll
    for (int nt = 0; nt < 5; nt++) cb[nt] = conv_b[f0 + nt * 16 + lm];
#pragma unroll
    for (int mt = 0; mt < 4; mt++) {
#pragma unroll
        for (int r = 0; r < 4; r++) {
            int lrow = rbase + mt * 16 + qq * 4 + r;
            int n = lrow & 31;
            int bglob = bid * 4 + (lrow >> 5);
            if (n < NN) {
#pragma unroll
                for (int nt = 0; nt < 5; nt++) {
                    float vv = fmaxf(acc[mt][nt][r] + cb[nt], 0.f);
                    Cws[((size_t)bglob * NN + n) * FILT + f0 + nt * 16 + lm] = f2bf(vv);
                }
            }
        }
    }
}

// ---------------- k2: pipelined attention-logit GEMM ----------------
// 960 blocks x 256 thr (4 waves x 32 rows), N=208, 13 K-steps of 32.
// B: DMA double-buffer (tiles split round-robin over waves); aF: depth-1 reg prefetch.
// Writes logits in [n][b] layout so k3's batch-dim softmax is coalesced.
__global__ __launch_bounds__(256, 2) void k2_att(
    const unsigned short* __restrict__ Cws,
    const unsigned short* __restrict__ Bv2,
    const float* __restrict__ vbp, const float* __restrict__ qp,
    float* __restrict__ a_out)
{
    __shared__ unsigned short Bs[2 * 13 * 512];   // 26,624 B
    const int lane = threadIdx.x & 63;
    const int wave = threadIdx.x >> 6;
    const int lm = lane & 15, qq = lane >> 4;
    const int r0 = blockIdx.x * 128 + wave * 32;

#pragma unroll
    for (int s = 0; s < 2; s++)
#pragma unroll
        for (int nt = 0; nt < 13; nt++)
            if ((nt & 3) == wave)
                dma16(Bv2 + (size_t)(s * 13 + nt) * 512 + lane * 8,
                      Bs + s * 6656 + nt * 512);

    bf16x8 aFc[2], aFn[2];
#pragma unroll
    for (int mt = 0; mt < 2; mt++)    // col overrun >=400 reads next row; B rows there are zero
        aFc[mt] = *(const bf16x8*)(Cws + (size_t)(r0 + mt * 16 + lm) * FILT + 8 * qq);

    f32x4 acc[2][13];
#pragma unroll
    for (int mt = 0; mt < 2; mt++)
#pragma unroll
        for (int nt = 0; nt < 13; nt++) acc[mt][nt] = (f32x4){0.f, 0.f, 0.f, 0.f};

    __syncthreads();                               // drains DMA 0,1

    for (int ks = 0; ks < 13; ++ks) {
        if (ks < 12)
#pragma unroll
            for (int mt = 0; mt < 2; mt++)
                aFn[mt] = *(const bf16x8*)(Cws + (size_t)(r0 + mt * 16 + lm) * FILT + (ks + 1) * 32 + 8 * qq);
        const unsigned short* bb = Bs + (ks & 1) * 6656;
#pragma unroll
        for (int nt = 0; nt < 13; nt++) {
            bf16x8 bF = *(const bf16x8*)(bb + nt * 512 + lane * 8);
#pragma unroll
            for (int mt = 0; mt < 2; mt++)
                acc[mt][nt] = __builtin_amdgcn_mfma_f32_16x16x32_bf16(aFc[mt], bF, acc[mt][nt], 0, 0, 0);
        }
        __syncthreads();
        if (ks + 2 < 13)
#pragma unroll
            for (int nt = 0; nt < 13; nt++)
                if ((nt & 3) == wave)
                    dma16(Bv2 + (size_t)((ks + 2) * 13 + nt) * 512 + lane * 8,
                          Bs + (ks & 1) * 6656 + nt * 512);
#pragma unroll
        for (int mt = 0; mt < 2; mt++) aFc[mt] = aFn[mt];
    }

#pragma unroll
    for (int mt = 0; mt < 2; mt++) {
        float rs[4] = {0.f, 0.f, 0.f, 0.f};
#pragma unroll
        for (int nt = 0; nt < 13; nt++) {
            int att = nt * 16 + lm;
            float vbv = vbp[att], qv = qp[att];
#pragma unroll
            for (int r = 0; r < 4; r++)
                rs[r] += fast_tanh(acc[mt][nt][r] + vbv) * qv;   // padded att: acc=0,q=0 -> 0
        }
#pragma unroll
        for (int off = 1; off < 16; off <<= 1)
#pragma unroll
            for (int r = 0; r < 4; r++) rs[r] += __shfl_xor(rs[r], off, 64);
        if (lm == 0) {
#pragma unroll
            for (int r = 0; r < 4; r++) {
                int rg = r0 + mt * 16 + qq * 4 + r;              // rg = b*30 + n
                a_out[(size_t)(rg % NN) * BB + (rg / NN)] = rs[r];  // [n][b] layout
            }
        }
    }
}

// ---------------- k3: softmax over batch dim, coalesced [n][b] layout, in-place ----------------
__global__ __launch_bounds__(1024) void k3_softmax(float* __restrict__ a,
                                                   const int* __restrict__ idx) {
    int n = blockIdx.x, tid = threadIdx.x;
    float4 v4 = *(const float4*)(a + (size_t)n * BB + tid * 4);
    float m = fmaxf(fmaxf(v4.x, v4.y), fmaxf(v4.z, v4.w));
    __shared__ float red[32];
#pragma unroll
    for (int off = 32; off >= 1; off >>= 1) m = fmaxf(m, __shfl_xor(m, off, 64));
    int wv = tid >> 6;
    if ((tid & 63) == 0) red[wv] = m;
    __syncthreads();
#pragma unroll
    for (int w = 0; w < 16; w++) m = fmaxf(m, red[w]);
    float e0 = expf(v4.x - m), e1 = expf(v4.y - m);
    float e2 = expf(v4.z - m), e3 = expf(v4.w - m);
    float s = e0 + e1 + e2 + e3;
#pragma unroll
    for (int off = 32; off >= 1; off >>= 1) s += __shfl_xor(s, off, 64);
    if ((tid & 63) == 0) red[16 + wv] = s;
    __syncthreads();
    s = 0.f;
#pragma unroll
    for (int w = 0; w < 16; w++) s += red[16 + w];
    float inv = 1.f / s;
    int b0 = tid * 4;
    float4 o;
    o.x = e0 * inv * ((idx[(size_t)(b0 + 0) * NN + n] != 0) ? 1.f : 0.f);
    o.y = e1 * inv * ((idx[(size_t)(b0 + 1) * NN + n] != 0) ? 1.f : 0.f);
    o.z = e2 * inv * ((idx[(size_t)(b0 + 2) * NN + n] != 0) ? 1.f : 0.f);
    o.w = e3 * inv * ((idx[(size_t)(b0 + 3) * NN + n] != 0) ? 1.f : 0.f);
    *(float4*)(a + (size_t)n * BB + b0) = o;
}

// ---------------- k4: weighted pooling, vectorized ----------------
__global__ __launch_bounds__(128) void k4_pool(
    const float* __restrict__ alpha, const unsigned short* __restrict__ C,
    float* __restrict__ out)
{
    int b = blockIdx.x;
    int tid = threadIdx.x;
    __shared__ float al[NN];
    if (tid < NN) al[tid] = alpha[(size_t)tid * BB + b];   // [n][b] layout
    __syncthreads();
    if (tid < 100) {
        int f = tid * 4;
        float s0 = 0.f, s1 = 0.f, s2 = 0.f, s3 = 0.f;
        const unsigned short* Cb = C + (size_t)b * (NN * FILT) + f;
#pragma unroll
        for (int n = 0; n < NN; n++) {
            u16x4 c = *(const u16x4*)(Cb + (size_t)n * FILT);
            float a = al[n];
            s0 = fmaf(a, bf2f(c[0]), s0);
            s1 = fmaf(a, bf2f(c[1]), s1);
            s2 = fmaf(a, bf2f(c[2]), s2);
            s3 = fmaf(a, bf2f(c[3]), s3);
        }
        float4 o; o.x = s0; o.y = s1; o.z = s2; o.w = s3;
        *(float4*)(out + (size_t)b * FILT + f) = o;
    }
}

extern "C" void kernel_launch(void* const* d_in, const int* in_sizes, int n_in,
                              void* d_out, int out_size, void* d_ws, size_t ws_size,
                              hipStream_t stream) {
    const int*   idx    = (const int*)d_in[0];
    const float* emb    = (const float*)d_in[1];
    const float* conv_w = (const float*)d_in[2];
    const float* conv_b = (const float*)d_in[3];
    const float* v      = (const float*)d_in[4];
    const float* vb     = (const float*)d_in[5];
    const float* q      = (const float*)d_in[6];
    float* out = (float*)d_out;

    // workspace (total 99,247,104 B <= 99,287,040 proven floor):
    //   Bv2 | vbp | qp | Bc2 (aliased by a_buf after k1) | Cws (+ slack for k2 row overrun)
    char* ws = (char*)d_ws;
    size_t o = 0;
    unsigned short* Bv2 = (unsigned short*)(ws + o); o += (size_t)169 * 512 * 2;      // 173,056
    float* vbp = (float*)(ws + o);                   o += 1024;
    float* qp  = (float*)(ws + o);                   o += 1024;                        // 175,104
    unsigned short* Bc2 = (unsigned short*)(ws + o);
    float* a_buf = (float*)(ws + o);                 // alias of Bc2 (491,520 <= 768,000; Bc2 dead after k1)
    o += (size_t)750 * 512 * 2;                      // -> 943,104
    unsigned short* Cws = (unsigned short*)(ws + o);

    const int NP = 750 * 512 + 169 * 512;            // 470,528
    kP<<<(NP + 255) / 256, 256, 0, stream>>>(conv_w, v, vb, q, Bc2, Bv2, vbp, qp);
    k1_conv<<<BB / 4, 640, 0, stream>>>(idx, emb, Bc2, conv_b, Cws);
    k2_att<<<(BB * NN) / 128, 256, 0, stream>>>(Cws, Bv2, vbp, qp, a_buf);
    k3_softmax<<<NN, 1024, 0, stream>>>(a_buf, idx);
    k4_pool<<<BB, 128, 0, stream>>>(a_buf, Cws, out);
}